// Round 5
// baseline (262.090 us; speedup 1.0000x reference)
//
#include <hip/hip_runtime.h>

#define Bv   2
#define Dd   160
#define Hh   192
#define Ww   160
#define HW   (Hh*Ww)          // 30720
#define DHW  (Dd*Hh*Ww)       // 4915200
#define NTOT (Bv*DHW)         // 9830400
#define INV729 (1.0f/729.0f)

typedef _Float16 f16;

// ---- vector helpers: storage type TS in {float, f16}, all math in f32 ----
__device__ __forceinline__ float4 LD4(const float* p) {
    return *reinterpret_cast<const float4*>(p);
}
__device__ __forceinline__ float4 LD4(const f16* p) {
    union { uint2 u; f16 h[4]; } c;
    c.u = *reinterpret_cast<const uint2*>(p);
    return make_float4((float)c.h[0], (float)c.h[1], (float)c.h[2], (float)c.h[3]);
}
__device__ __forceinline__ void ST4(float* p, float4 v) {
    *reinterpret_cast<float4*>(p) = v;
}
__device__ __forceinline__ void ST4(f16* p, float4 v) {
    union { uint2 u; f16 h[4]; } c;
    c.h[0] = (f16)v.x; c.h[1] = (f16)v.y; c.h[2] = (f16)v.z; c.h[3] = (f16)v.w;
    *reinterpret_cast<uint2*>(p) = c.u;
}
__device__ __forceinline__ float4 add4(float4 a, float4 b) {
    return make_float4(a.x+b.x, a.y+b.y, a.z+b.z, a.w+b.w);
}
__device__ __forceinline__ float4 sub4(float4 a, float4 b) {
    return make_float4(a.x-b.x, a.y-b.y, a.z-b.z, a.w-b.w);
}
__device__ __forceinline__ float4 zero4() { return make_float4(0.f,0.f,0.f,0.f); }

// ---- rowsum5: add sgn * (5-channel 9-wide x-box-sums at 4 x-positions) into S ----
// Reads row rI/rJ at x-window [x0-4, x0+7]; OOB x treated as zero.
__device__ __forceinline__ void rowsum5(const float* __restrict__ rI,
                                        const float* __restrict__ rJ,
                                        int x0, float sgn, float4 S[5]) {
    float wI[12], wJ[12];
    if (x0 >= 4 && x0 <= Ww - 8) {                     // fast interior path
        float4 a0 = LD4(rI + x0 - 4), a1 = LD4(rI + x0), a2 = LD4(rI + x0 + 4);
        wI[0]=a0.x; wI[1]=a0.y; wI[2]=a0.z;  wI[3]=a0.w;
        wI[4]=a1.x; wI[5]=a1.y; wI[6]=a1.z;  wI[7]=a1.w;
        wI[8]=a2.x; wI[9]=a2.y; wI[10]=a2.z; wI[11]=a2.w;
        float4 b0 = LD4(rJ + x0 - 4), b1 = LD4(rJ + x0), b2 = LD4(rJ + x0 + 4);
        wJ[0]=b0.x; wJ[1]=b0.y; wJ[2]=b0.z;  wJ[3]=b0.w;
        wJ[4]=b1.x; wJ[5]=b1.y; wJ[6]=b1.z;  wJ[7]=b1.w;
        wJ[8]=b2.x; wJ[9]=b2.y; wJ[10]=b2.z; wJ[11]=b2.w;
    } else {
        #pragma unroll
        for (int i = 0; i < 12; ++i) {
            int xx = x0 - 4 + i;
            bool ok = (xx >= 0) && (xx < Ww);
            wI[i] = ok ? rI[xx] : 0.f;
            wJ[i] = ok ? rJ[xx] : 0.f;
        }
    }
#define CH(cidx, EXPR) {                                                    \
        float t[12];                                                        \
        _Pragma("unroll")                                                   \
        for (int i = 0; i < 12; ++i) {                                      \
            float a = wI[i], b = wJ[i]; (void)a; (void)b;                   \
            t[i] = (EXPR);                                                  \
        }                                                                   \
        float s0 = ((t[0]+t[1])+(t[2]+t[3]))+((t[4]+t[5])+(t[6]+t[7]))+t[8];\
        float s1 = s0 - t[0] + t[9];                                        \
        float s2 = s1 - t[1] + t[10];                                       \
        float s3 = s2 - t[2] + t[11];                                       \
        S[cidx].x += sgn * s0; S[cidx].y += sgn * s1;                       \
        S[cidx].z += sgn * s2; S[cidx].w += sgn * s3;                       \
    }
    CH(0, a); CH(1, b); CH(2, a * a); CH(3, b * b); CH(4, a * b);
#undef CH
}

// ---- cc4: finalize 4 voxels from 5-channel window sums, return their cc sum ----
__device__ __forceinline__ float cc4(const float4 S[5]) {
    float acc = 0.f;
#define FIN(CMP) {                                                      \
        float SI = S[0].CMP, SJ = S[1].CMP, SII = S[2].CMP,             \
              SJJ = S[3].CMP, SIJ = S[4].CMP;                           \
        float uI = SI * INV729, uJ = SJ * INV729;                       \
        float cross = SIJ - uJ * SI - uI * SJ + uI * uJ * 729.0f;       \
        float Iv = SII - 2.0f * uI * SI + uI * uI * 729.0f;             \
        float Jv = SJJ - 2.0f * uJ * SJ + uJ * uJ * 729.0f;             \
        acc += cross * cross / (Iv * Jv + 1e-5f);                       \
    }
    FIN(x) FIN(y) FIN(z) FIN(w)
#undef FIN
    return acc;
}

__device__ __forceinline__ void block_reduce_atomic(float acc, float* out) {
    for (int off = 32; off > 0; off >>= 1) acc += __shfl_down(acc, off);
    __shared__ float red[4];
    int lane = threadIdx.x & 63, wid = threadIdx.x >> 6;
    if (lane == 0) red[wid] = acc;
    __syncthreads();
    if (threadIdx.x == 0)
        atomicAdd(out, (red[0]+red[1]+red[2]+red[3]) * (1.0f/(float)NTOT));
}

// ---------------- k12: fused x+y pass -> 5-channel xy-box-sums ----------------
// thread -> (b, z, y-chunk of 16, 4 consecutive x); y-running-window,
// row x-sums recomputed on add/sub (input slice is L2-resident).
template<typename TS>
__global__ __launch_bounds__(256)
void k12_xy(const float* __restrict__ I, const float* __restrict__ J,
            TS* __restrict__ B) {
    int tid = blockIdx.x * 256 + threadIdx.x;          // 0 .. 153599
    int x4 = tid % (Ww/4);  int t1 = tid / (Ww/4);
    int yc = t1 % 12;       t1 /= 12;
    int z  = t1 % Dd;       int b = t1 / Dd;
    int x0 = x4 * 4, y0 = yc * 16;

    const float* sI = I + (size_t)b * DHW + (size_t)z * HW;
    const float* sJ = J + (size_t)b * DHW + (size_t)z * HW;
    TS* dst = B + (size_t)b * DHW + (size_t)z * HW + x0;

    float4 S[5] = {zero4(), zero4(), zero4(), zero4(), zero4()};
    #pragma unroll
    for (int dy = -4; dy <= 3; ++dy) {                 // preload y0-4 .. y0+3
        int y = y0 + dy;
        if (y >= 0) rowsum5(sI + (size_t)y * Ww, sJ + (size_t)y * Ww, x0, 1.f, S);
    }
    for (int y = y0; y < y0 + 16; ++y) {
        int yt = y + 4;
        if (yt < Hh) rowsum5(sI + (size_t)yt * Ww, sJ + (size_t)yt * Ww, x0, 1.f, S);
        ST4(dst + (size_t)y * Ww,               S[0]);
        ST4(dst + (size_t)NTOT     + (size_t)y * Ww, S[1]);
        ST4(dst + (size_t)2 * NTOT + (size_t)y * Ww, S[2]);
        ST4(dst + (size_t)3 * NTOT + (size_t)y * Ww, S[3]);
        ST4(dst + (size_t)4 * NTOT + (size_t)y * Ww, S[4]);
        int yo = y - 4;
        if (yo >= 0) rowsum5(sI + (size_t)yo * Ww, sJ + (size_t)yo * Ww, x0, -1.f, S);
    }
}

// ---------------- k3: z-pass + finalize + global mean ----------------
// thread -> (b, z-chunk of 16, y, 4 consecutive x); all 5 channels at once.
template<typename TS>
__global__ __launch_bounds__(256)
void k3_zpass(const TS* __restrict__ Bb, float* __restrict__ out) {
    int tid = blockIdx.x * 256 + threadIdx.x;          // 0 .. 153599
    int x4 = tid % (Ww/4);  int t1 = tid / (Ww/4);
    int y  = t1 % Hh;       t1 /= Hh;
    int zc = t1 % 10;       int b = t1 / 10;
    int z0 = zc * 16;

    size_t base = (size_t)b * DHW + (size_t)y * Ww + x4 * 4;
    const TS* P0 = Bb + base;

    float4 S[5] = {zero4(), zero4(), zero4(), zero4(), zero4()};

#define LOADADD(zi) {                                                   \
        const TS* pp = P0 + (size_t)(zi) * HW;                          \
        S[0] = add4(S[0], LD4(pp));                                     \
        S[1] = add4(S[1], LD4(pp + (size_t)NTOT));                      \
        S[2] = add4(S[2], LD4(pp + (size_t)2 * NTOT));                  \
        S[3] = add4(S[3], LD4(pp + (size_t)3 * NTOT));                  \
        S[4] = add4(S[4], LD4(pp + (size_t)4 * NTOT));                  \
    }
#define LOADSUB(zi) {                                                   \
        const TS* pp = P0 + (size_t)(zi) * HW;                          \
        S[0] = sub4(S[0], LD4(pp));                                     \
        S[1] = sub4(S[1], LD4(pp + (size_t)NTOT));                      \
        S[2] = sub4(S[2], LD4(pp + (size_t)2 * NTOT));                  \
        S[3] = sub4(S[3], LD4(pp + (size_t)3 * NTOT));                  \
        S[4] = sub4(S[4], LD4(pp + (size_t)4 * NTOT));                  \
    }

    #pragma unroll
    for (int dz = -4; dz <= 3; ++dz) {                 // preload z0-4 .. z0+3
        int z = z0 + dz;
        if (z >= 0) LOADADD(z);
    }

    float acc = 0.f;
    for (int z = z0; z < z0 + 16; ++z) {
        int zt = z + 4;
        if (zt < Dd) LOADADD(zt);
        acc += cc4(S);
        int zo = z - 4;
        if (zo >= 0) LOADSUB(zo);
    }
#undef LOADADD
#undef LOADSUB

    block_reduce_atomic(acc, out);
}

// ---------------- brute-force fallback: ZERO workspace, slow but correct ----
// thread -> (b, z, y, 4 consecutive x); direct 9x9 row-sum accumulation.
__global__ __launch_bounds__(256)
void k_brute(const float* __restrict__ I, const float* __restrict__ J,
             float* __restrict__ out) {
    int tid = blockIdx.x * 256 + threadIdx.x;          // 0 .. NTOT/4-1
    int x4 = tid % (Ww/4);  int t1 = tid / (Ww/4);
    int y  = t1 % Hh;       t1 /= Hh;
    int z  = t1 % Dd;       int b = t1 / Dd;
    int x0 = x4 * 4;

    const float* bI = I + (size_t)b * DHW;
    const float* bJ = J + (size_t)b * DHW;

    float4 S[5] = {zero4(), zero4(), zero4(), zero4(), zero4()};
    for (int dz = -4; dz <= 4; ++dz) {
        int zz = z + dz;
        if (zz < 0 || zz >= Dd) continue;
        for (int dy = -4; dy <= 4; ++dy) {
            int yy = y + dy;
            if (yy < 0 || yy >= Hh) continue;
            rowsum5(bI + (size_t)zz * HW + (size_t)yy * Ww,
                    bJ + (size_t)zz * HW + (size_t)yy * Ww, x0, 1.f, S);
        }
    }
    block_reduce_atomic(cc4(S), out);
}

extern "C" void kernel_launch(void* const* d_in, const int* in_sizes, int n_in,
                              void* d_out, int out_size, void* d_ws, size_t ws_size,
                              hipStream_t stream) {
    const float* I = (const float*)d_in[0];
    const float* J = (const float*)d_in[1];
    float* out = (float*)d_out;

    hipMemsetAsync(d_out, 0, sizeof(float), stream);   // graph-capture-safe

    const int g12 = (Bv*Dd*12*(Ww/4)*16/16)*16/256 ;   // 153600/256
    const int gk  = 153600/256;                        // 600 blocks (k12 and k3)
    (void)g12;

    if (ws_size >= (size_t)5 * NTOT * sizeof(float)) {
        // f32 intermediates: one 5-channel xy-sum buffer (196.6 MB)
        float* B = (float*)d_ws;
        k12_xy<float><<<gk, 256, 0, stream>>>(I, J, B);
        k3_zpass<float><<<gk, 256, 0, stream>>>(B, out);
    } else if (ws_size >= (size_t)5 * NTOT * sizeof(f16)) {
        // f16 intermediates (98.3 MB), math in f32
        f16* B = (f16*)d_ws;
        k12_xy<f16><<<gk, 256, 0, stream>>>(I, J, B);
        k3_zpass<f16><<<gk, 256, 0, stream>>>(B, out);
    } else {
        // workspace-free fallback: slow but correct
        k_brute<<<(NTOT/4)/256, 256, 0, stream>>>(I, J, out);
    }
}

// Round 10
// 235.288 us; speedup vs baseline: 1.1139x; 1.1139x over previous
//
#include <hip/hip_runtime.h>

#define Bv   2
#define Dd   160
#define Hh   192
#define Ww   160
#define HW   (Hh*Ww)          // 30720
#define DHW  (Dd*Hh*Ww)       // 4915200
#define NTOT (Bv*DHW)         // 9830400
#define INV729 (1.0f/729.0f)

typedef _Float16 f16;

// ---- vector helpers: storage type TS in {float, f16}, all math in f32 ----
__device__ __forceinline__ float4 LD4(const float* p) {
    return *reinterpret_cast<const float4*>(p);
}
__device__ __forceinline__ float4 LD4(const f16* p) {
    union { uint2 u; f16 h[4]; } c;
    c.u = *reinterpret_cast<const uint2*>(p);
    return make_float4((float)c.h[0], (float)c.h[1], (float)c.h[2], (float)c.h[3]);
}
__device__ __forceinline__ void ST4(float* p, float4 v) {
    *reinterpret_cast<float4*>(p) = v;
}
__device__ __forceinline__ void ST4(f16* p, float4 v) {
    union { uint2 u; f16 h[4]; } c;
    c.h[0] = (f16)v.x; c.h[1] = (f16)v.y; c.h[2] = (f16)v.z; c.h[3] = (f16)v.w;
    *reinterpret_cast<uint2*>(p) = c.u;
}
__device__ __forceinline__ float4 add4(float4 a, float4 b) {
    return make_float4(a.x+b.x, a.y+b.y, a.z+b.z, a.w+b.w);
}
__device__ __forceinline__ float4 sub4(float4 a, float4 b) {
    return make_float4(a.x-b.x, a.y-b.y, a.z-b.z, a.w-b.w);
}
__device__ __forceinline__ float4 zero4() { return make_float4(0.f,0.f,0.f,0.f); }

// ---- rowsum5: add sgn * (5-channel 9-wide x-box-sums at 4 x-positions) into S ----
__device__ __forceinline__ void rowsum5(const float* __restrict__ rI,
                                        const float* __restrict__ rJ,
                                        int x0, float sgn, float4 S[5]) {
    float wI[12], wJ[12];
    if (x0 >= 4 && x0 <= Ww - 8) {                     // fast interior path
        float4 a0 = LD4(rI + x0 - 4), a1 = LD4(rI + x0), a2 = LD4(rI + x0 + 4);
        wI[0]=a0.x; wI[1]=a0.y; wI[2]=a0.z;  wI[3]=a0.w;
        wI[4]=a1.x; wI[5]=a1.y; wI[6]=a1.z;  wI[7]=a1.w;
        wI[8]=a2.x; wI[9]=a2.y; wI[10]=a2.z; wI[11]=a2.w;
        float4 b0 = LD4(rJ + x0 - 4), b1 = LD4(rJ + x0), b2 = LD4(rJ + x0 + 4);
        wJ[0]=b0.x; wJ[1]=b0.y; wJ[2]=b0.z;  wJ[3]=b0.w;
        wJ[4]=b1.x; wJ[5]=b1.y; wJ[6]=b1.z;  wJ[7]=b1.w;
        wJ[8]=b2.x; wJ[9]=b2.y; wJ[10]=b2.z; wJ[11]=b2.w;
    } else {
        #pragma unroll
        for (int i = 0; i < 12; ++i) {
            int xx = x0 - 4 + i;
            bool ok = (xx >= 0) && (xx < Ww);
            wI[i] = ok ? rI[xx] : 0.f;
            wJ[i] = ok ? rJ[xx] : 0.f;
        }
    }
#define CH(cidx, EXPR) {                                                    \
        float t[12];                                                        \
        _Pragma("unroll")                                                   \
        for (int i = 0; i < 12; ++i) {                                      \
            float a = wI[i], b = wJ[i]; (void)a; (void)b;                   \
            t[i] = (EXPR);                                                  \
        }                                                                   \
        float s0 = ((t[0]+t[1])+(t[2]+t[3]))+((t[4]+t[5])+(t[6]+t[7]))+t[8];\
        float s1 = s0 - t[0] + t[9];                                        \
        float s2 = s1 - t[1] + t[10];                                       \
        float s3 = s2 - t[2] + t[11];                                       \
        S[cidx].x += sgn * s0; S[cidx].y += sgn * s1;                       \
        S[cidx].z += sgn * s2; S[cidx].w += sgn * s3;                       \
    }
    CH(0, a); CH(1, b); CH(2, a * a); CH(3, b * b); CH(4, a * b);
#undef CH
}

// ---- cc4: finalize 4 voxels from 5-channel window sums, return their cc sum ----
__device__ __forceinline__ float cc4(const float4 S[5]) {
    float acc = 0.f;
#define FIN(CMP) {                                                      \
        float SI = S[0].CMP, SJ = S[1].CMP, SII = S[2].CMP,             \
              SJJ = S[3].CMP, SIJ = S[4].CMP;                           \
        float uI = SI * INV729, uJ = SJ * INV729;                       \
        float cross = SIJ - uJ * SI - uI * SJ + uI * uJ * 729.0f;       \
        float Iv = SII - 2.0f * uI * SI + uI * uI * 729.0f;             \
        float Jv = SJJ - 2.0f * uJ * SJ + uJ * uJ * 729.0f;             \
        acc += cross * cross / (Iv * Jv + 1e-5f);                       \
    }
    FIN(x) FIN(y) FIN(z) FIN(w)
#undef FIN
    return acc;
}

__device__ __forceinline__ void block_reduce_atomic(float acc, float* out) {
    for (int off = 32; off > 0; off >>= 1) acc += __shfl_down(acc, off);
    __shared__ float red[4];
    int lane = threadIdx.x & 63, wid = threadIdx.x >> 6;
    if (lane == 0) red[wid] = acc;
    __syncthreads();
    if (threadIdx.x == 0)
        atomicAdd(out, (red[0]+red[1]+red[2]+red[3]) * (1.0f/(float)NTOT));
}

// ---------------- k12: fused x+y pass -> 5-channel xy-box-sums ----------------
// thread -> (b, z, y-chunk of 8, 4 consecutive x); y-running-window,
// row x-sums recomputed on add/sub (input slice is L2-resident).
// y-chunk=8 -> 1200 blocks (~19 waves/CU @48 VGPR) for latency hiding.
template<typename TS>
__global__ __launch_bounds__(256)
void k12_xy(const float* __restrict__ I, const float* __restrict__ J,
            TS* __restrict__ B) {
    int tid = blockIdx.x * 256 + threadIdx.x;          // 0 .. 307199
    int x4 = tid % (Ww/4);  int t1 = tid / (Ww/4);
    int yc = t1 % (Hh/8);   t1 /= (Hh/8);
    int z  = t1 % Dd;       int b = t1 / Dd;
    int x0 = x4 * 4, y0 = yc * 8;

    const float* sI = I + (size_t)b * DHW + (size_t)z * HW;
    const float* sJ = J + (size_t)b * DHW + (size_t)z * HW;
    TS* dst = B + (size_t)b * DHW + (size_t)z * HW + x0;

    float4 S[5] = {zero4(), zero4(), zero4(), zero4(), zero4()};
    #pragma unroll
    for (int dy = -4; dy <= 3; ++dy) {                 // preload y0-4 .. y0+3
        int y = y0 + dy;
        if (y >= 0) rowsum5(sI + (size_t)y * Ww, sJ + (size_t)y * Ww, x0, 1.f, S);
    }
    #pragma unroll
    for (int y = y0; y < y0 + 8; ++y) {
        int yt = y + 4;
        if (yt < Hh) rowsum5(sI + (size_t)yt * Ww, sJ + (size_t)yt * Ww, x0, 1.f, S);
        ST4(dst + (size_t)y * Ww,                    S[0]);
        ST4(dst + (size_t)NTOT     + (size_t)y * Ww, S[1]);
        ST4(dst + (size_t)2 * NTOT + (size_t)y * Ww, S[2]);
        ST4(dst + (size_t)3 * NTOT + (size_t)y * Ww, S[3]);
        ST4(dst + (size_t)4 * NTOT + (size_t)y * Ww, S[4]);
        int yo = y - 4;
        if (yo >= 0) rowsum5(sI + (size_t)yo * Ww, sJ + (size_t)yo * Ww, x0, -1.f, S);
    }
}

// ---------------- k3: z-pass + finalize + global mean ----------------
// thread -> (b, z-chunk of 8, y, 4 consecutive x); all 5 channels at once.
template<typename TS>
__global__ __launch_bounds__(256)
void k3_zpass(const TS* __restrict__ Bb, float* __restrict__ out) {
    int tid = blockIdx.x * 256 + threadIdx.x;          // 0 .. 307199
    int x4 = tid % (Ww/4);  int t1 = tid / (Ww/4);
    int y  = t1 % Hh;       t1 /= Hh;
    int zc = t1 % (Dd/8);   int b = t1 / (Dd/8);
    int z0 = zc * 8;

    size_t base = (size_t)b * DHW + (size_t)y * Ww + x4 * 4;
    const TS* P0 = Bb + base;

    float4 S[5] = {zero4(), zero4(), zero4(), zero4(), zero4()};

#define LOADADD(zi) {                                                   \
        const TS* pp = P0 + (size_t)(zi) * HW;                          \
        S[0] = add4(S[0], LD4(pp));                                     \
        S[1] = add4(S[1], LD4(pp + (size_t)NTOT));                      \
        S[2] = add4(S[2], LD4(pp + (size_t)2 * NTOT));                  \
        S[3] = add4(S[3], LD4(pp + (size_t)3 * NTOT));                  \
        S[4] = add4(S[4], LD4(pp + (size_t)4 * NTOT));                  \
    }
#define LOADSUB(zi) {                                                   \
        const TS* pp = P0 + (size_t)(zi) * HW;                          \
        S[0] = sub4(S[0], LD4(pp));                                     \
        S[1] = sub4(S[1], LD4(pp + (size_t)NTOT));                      \
        S[2] = sub4(S[2], LD4(pp + (size_t)2 * NTOT));                  \
        S[3] = sub4(S[3], LD4(pp + (size_t)3 * NTOT));                  \
        S[4] = sub4(S[4], LD4(pp + (size_t)4 * NTOT));                  \
    }

    #pragma unroll
    for (int dz = -4; dz <= 3; ++dz) {                 // preload z0-4 .. z0+3
        int z = z0 + dz;
        if (z >= 0) LOADADD(z);
    }

    float acc = 0.f;
    #pragma unroll
    for (int z = z0; z < z0 + 8; ++z) {
        int zt = z + 4;
        if (zt < Dd) LOADADD(zt);
        acc += cc4(S);
        int zo = z - 4;
        if (zo >= 0) LOADSUB(zo);
    }
#undef LOADADD
#undef LOADSUB

    block_reduce_atomic(acc, out);
}

// ---------------- brute-force fallback: ZERO workspace, slow but correct ----
__global__ __launch_bounds__(256)
void k_brute(const float* __restrict__ I, const float* __restrict__ J,
             float* __restrict__ out) {
    int tid = blockIdx.x * 256 + threadIdx.x;          // 0 .. NTOT/4-1
    int x4 = tid % (Ww/4);  int t1 = tid / (Ww/4);
    int y  = t1 % Hh;       t1 /= Hh;
    int z  = t1 % Dd;       int b = t1 / Dd;
    int x0 = x4 * 4;

    const float* bI = I + (size_t)b * DHW;
    const float* bJ = J + (size_t)b * DHW;

    float4 S[5] = {zero4(), zero4(), zero4(), zero4(), zero4()};
    for (int dz = -4; dz <= 4; ++dz) {
        int zz = z + dz;
        if (zz < 0 || zz >= Dd) continue;
        for (int dy = -4; dy <= 4; ++dy) {
            int yy = y + dy;
            if (yy < 0 || yy >= Hh) continue;
            rowsum5(bI + (size_t)zz * HW + (size_t)yy * Ww,
                    bJ + (size_t)zz * HW + (size_t)yy * Ww, x0, 1.f, S);
        }
    }
    block_reduce_atomic(cc4(S), out);
}

extern "C" void kernel_launch(void* const* d_in, const int* in_sizes, int n_in,
                              void* d_out, int out_size, void* d_ws, size_t ws_size,
                              hipStream_t stream) {
    const float* I = (const float*)d_in[0];
    const float* J = (const float*)d_in[1];
    float* out = (float*)d_out;

    hipMemsetAsync(d_out, 0, sizeof(float), stream);   // graph-capture-safe

    const int gk = 307200/256;                         // 1200 blocks

    if (ws_size >= (size_t)5 * NTOT * sizeof(f16)) {
        // f16 intermediates (98.3 MB), all math f32.
        // Error budget: f16 rel 4.9e-4 on ~81-scale xy-sums -> ~1.3e-6 on the
        // mean, ~20x under the 2.88e-5 threshold (round-5 f32 run: absmax 0.0).
        f16* B = (f16*)d_ws;
        k12_xy<f16><<<gk, 256, 0, stream>>>(I, J, B);
        k3_zpass<f16><<<gk, 256, 0, stream>>>(B, out);
    } else {
        // workspace-free fallback: slow but correct
        k_brute<<<(NTOT/4)/256, 256, 0, stream>>>(I, J, out);
    }
}